// Round 2
// baseline (121.021 us; speedup 1.0000x reference)
//
#include <hip/hip_runtime.h>

#define NUM_LABELS 20
#define N_PIX 4096
#define C_DIM 16
#define BATCH 4

#define PTILE 128
#define PNT (N_PIX / PTILE)               // 32
#define PTPAIRS (PNT * (PNT + 1) / 2)     // 528

// ---------------- Kernel A: normalize, fold weights (g = w*e), centroids ----
// Also emits the closed-form positive-pair term per batch:
//   A_b = 0.5 * (#present_labels - sum_l ||m_l||^2),  m_l = sum_{y_i=l} g_i
__global__ __launch_bounds__(1024) void prep_kernel(
    const float* __restrict__ emb,   // [B][C][N]
    const int*   __restrict__ lab,   // [B][N]
    float* __restrict__ g_out,       // [B][C][N]  (g = w * e)
    float* __restrict__ partials)    // A_b at [BATCH*PTPAIRS + b]
{
    const int b = blockIdx.x;
    const int t = threadIdx.x;
    const int wave = t >> 6;

    __shared__ int   cnt[NUM_LABELS];
    __shared__ float msl[16][NUM_LABELS * C_DIM];   // per-wave centroid slabs
    __shared__ float mtot[NUM_LABELS * C_DIM];

    for (int i = t; i < NUM_LABELS; i += 1024) cnt[i] = 0;
    for (int i = t; i < 16 * NUM_LABELS * C_DIM; i += 1024)
        (&msl[0][0])[i] = 0.f;
    __syncthreads();

    const float* xb = emb + (size_t)b * C_DIM * N_PIX;
    const int*   yb = lab + (size_t)b * N_PIX;
    float*       gb = g_out + (size_t)b * C_DIM * N_PIX;

    for (int n = t; n < N_PIX; n += 1024) atomicAdd(&cnt[yb[n]], 1);
    __syncthreads();

    for (int n = t; n < N_PIX; n += 1024) {
        float v[C_DIM];
        float s = 0.f;
#pragma unroll
        for (int c = 0; c < C_DIM; ++c) { v[c] = xb[c * N_PIX + n]; s += v[c]; }
        const float mean = s * (1.0f / C_DIM);
        float ss = 0.f;
#pragma unroll
        for (int c = 0; c < C_DIM; ++c) { v[c] -= mean; ss += v[c] * v[c]; }
        const float nrm = sqrtf(ss);
        const int   y   = yb[n];
        const float w   = 1.0f / (float)cnt[y];
        const float inv = (nrm > 0.f) ? (w / nrm) : 0.f;
#pragma unroll
        for (int c = 0; c < C_DIM; ++c) {
            const float gv = v[c] * inv;
            gb[c * N_PIX + n] = gv;
            atomicAdd(&msl[wave][y * C_DIM + c], gv);
        }
    }
    __syncthreads();

    if (t < NUM_LABELS * C_DIM) {
        float s = 0.f;
#pragma unroll
        for (int w = 0; w < 16; ++w) s += msl[w][t];
        mtot[t] = s;
    }
    __syncthreads();

    if (t < 64) {
        float s = 0.f;
        for (int i = t; i < NUM_LABELS * C_DIM; i += 64) s += mtot[i] * mtot[i];
#pragma unroll
        for (int off = 32; off > 0; off >>= 1) s += __shfl_down(s, off);
        if (t == 0) {
            int present = 0;
#pragma unroll
            for (int l = 0; l < NUM_LABELS; ++l) present += (cnt[l] > 0) ? 1 : 0;
            partials[BATCH * PTPAIRS + b] = 0.5f * ((float)present - s);
        }
    }
}

// ---------------- Kernel B: negative-pair sum over upper-triangle tiles -----
// NE_b = sum_{i<j, y_i!=y_j} max(g_i . g_j, 0)   (ordered-pair 0.5*2 folded)
__global__ __launch_bounds__(256) void pair_kernel(
    const float* __restrict__ g,     // [B][C][N]
    const int*   __restrict__ lab,   // [B][N]
    float* __restrict__ partials)    // [B*PTPAIRS]
{
    const int k0 = blockIdx.x % PTPAIRS;
    const int b  = blockIdx.x / PTPAIRS;

    // decode upper-triangle tile pair (ti <= tj), NT = 32
    const float nn = (float)PNT;
    int ti = (int)(((2.f * nn + 1.f) -
                    sqrtf((2.f * nn + 1.f) * (2.f * nn + 1.f) - 8.f * (float)k0)) * 0.5f);
    if (ti < 0) ti = 0;
    if (ti > PNT - 1) ti = PNT - 1;
    auto rowoff = [](int r) { return r * PNT - (r * (r - 1)) / 2; };
    while (ti > 0 && k0 < rowoff(ti)) --ti;
    while (ti < PNT - 1 && k0 >= rowoff(ti + 1)) ++ti;
    const int tj = ti + (k0 - rowoff(ti));
    const bool diag = (ti == tj);

    __shared__ float gI[C_DIM][PTILE];
    __shared__ float gJ[C_DIM][PTILE];
    __shared__ int   yI[PTILE], yJ[PTILE];

    const int t = threadIdx.x;
    const float* gb = g + (size_t)b * C_DIM * N_PIX;

    for (int idx = t; idx < C_DIM * (PTILE / 4); idx += 256) {
        const int c  = idx >> 5;     // 32 float4 per row
        const int qd = idx & 31;
        const float4 vI = *reinterpret_cast<const float4*>(gb + c * N_PIX + ti * PTILE + qd * 4);
        const float4 vJ = *reinterpret_cast<const float4*>(gb + c * N_PIX + tj * PTILE + qd * 4);
        *reinterpret_cast<float4*>(&gI[c][qd * 4]) = vI;
        *reinterpret_cast<float4*>(&gJ[c][qd * 4]) = vJ;
    }
    if (t < PTILE) {
        yI[t] = lab[(size_t)b * N_PIX + ti * PTILE + t];
    } else {
        const int u = t - PTILE;
        yJ[u] = lab[(size_t)b * N_PIX + tj * PTILE + u];
    }
    __syncthreads();

    const int tI = t >> 4;   // 0..15 (rows group of 8)
    const int tJ = t & 15;   // 0..15 (cols group of 8)

    float acc[8][8];
#pragma unroll
    for (int a = 0; a < 8; ++a)
#pragma unroll
        for (int q = 0; q < 8; ++q) acc[a][q] = 0.f;

#pragma unroll
    for (int c = 0; c < C_DIM; ++c) {
        const float4 a0 = *reinterpret_cast<const float4*>(&gI[c][tI * 8]);
        const float4 a1 = *reinterpret_cast<const float4*>(&gI[c][tI * 8 + 4]);
        const float4 b0 = *reinterpret_cast<const float4*>(&gJ[c][tJ * 8]);
        const float4 b1 = *reinterpret_cast<const float4*>(&gJ[c][tJ * 8 + 4]);
        const float aa[8] = {a0.x, a0.y, a0.z, a0.w, a1.x, a1.y, a1.z, a1.w};
        const float bb[8] = {b0.x, b0.y, b0.z, b0.w, b1.x, b1.y, b1.z, b1.w};
#pragma unroll
        for (int a = 0; a < 8; ++a)
#pragma unroll
            for (int q = 0; q < 8; ++q) acc[a][q] = fmaf(aa[a], bb[q], acc[a][q]);
    }

    int ya[8], yq[8];
#pragma unroll
    for (int a = 0; a < 8; ++a) ya[a] = yI[tI * 8 + a];
#pragma unroll
    for (int q = 0; q < 8; ++q) yq[q] = yJ[tJ * 8 + q];

    float sum = 0.f;
    if (!diag) {
#pragma unroll
        for (int a = 0; a < 8; ++a)
#pragma unroll
            for (int q = 0; q < 8; ++q)
                sum += (ya[a] != yq[q]) ? fmaxf(acc[a][q], 0.f) : 0.f;
    } else {
#pragma unroll
        for (int a = 0; a < 8; ++a) {
            const int i = tI * 8 + a;
#pragma unroll
            for (int q = 0; q < 8; ++q) {
                const int j = tJ * 8 + q;
                sum += (i < j && ya[a] != yq[q]) ? fmaxf(acc[a][q], 0.f) : 0.f;
            }
        }
    }

    // block reduction: wave shuffle + LDS across 4 waves
#pragma unroll
    for (int off = 32; off > 0; off >>= 1) sum += __shfl_down(sum, off);
    __shared__ float wred[4];
    if ((t & 63) == 0) wred[t >> 6] = sum;
    __syncthreads();
    if (t == 0) partials[(size_t)b * PTPAIRS + k0] = wred[0] + wred[1] + wred[2] + wred[3];
}

// ---------------- Kernel C: deterministic final reduce ----------------------
__global__ __launch_bounds__(256) void reduce_kernel(
    const float* __restrict__ partials, int n, float* __restrict__ out)
{
    __shared__ double sd[256];
    const int t = threadIdx.x;
    double s = 0.0;
    for (int i = t; i < n; i += 256) s += (double)partials[i];
    sd[t] = s;
    __syncthreads();
#pragma unroll
    for (int k = 128; k > 0; k >>= 1) {
        if (t < k) sd[t] += sd[t + k];
        __syncthreads();
    }
    if (t == 0) out[0] = (float)(sd[0] * (1.0 / (double)N_PIX));
}

extern "C" void kernel_launch(void* const* d_in, const int* in_sizes, int n_in,
                              void* d_out, int out_size, void* d_ws, size_t ws_size,
                              hipStream_t stream) {
    const float* emb = (const float*)d_in[0];
    const int*   lab = (const int*)d_in[1];
    float* out = (float*)d_out;

    float* ws = (float*)d_ws;
    float* g_buf    = ws;                                      // B*C*N = 262144 floats
    float* partials = g_buf + (size_t)BATCH * C_DIM * N_PIX;   // B*PTPAIRS + B floats

    prep_kernel<<<BATCH, 1024, 0, stream>>>(emb, lab, g_buf, partials);
    pair_kernel<<<BATCH * PTPAIRS, 256, 0, stream>>>(g_buf, lab, partials);
    reduce_kernel<<<1, 256, 0, stream>>>(partials, BATCH * PTPAIRS + BATCH, out);
}

// Round 4
// 71.793 us; speedup vs baseline: 1.6857x; 1.6857x over previous
//
#include <hip/hip_runtime.h>

#define NUM_LABELS 20
#define N_PIX 4096
#define C_DIM 16
#define BATCH 4

#define PTILE 128
#define PNT (N_PIX / PTILE)               // 32
#define PTPAIRS (PNT * (PNT + 1) / 2)     // 528
#define NPAIRBLK (BATCH * PTPAIRS)        // 2112

#define PREP_SLICES 16                    // blocks per batch
#define PREP_PIX (N_PIX / PREP_SLICES)    // 256 pixels per block

// ---------------- Kernel A: histogram (redundant per block) + normalize -----
// g = (1/cnt[y]) * normalize(center(x));  w = 1/cnt[y]
__global__ __launch_bounds__(256) void prep_kernel(
    const float* __restrict__ emb,   // [B][C][N]
    const int*   __restrict__ lab,   // [B][N]
    float* __restrict__ g_out,       // [B][C][N]
    float* __restrict__ w_out,       // [B][N]
    int*   __restrict__ counter)     // ticket counter for pair kernel
{
    const int blk = blockIdx.x;
    if (blk == 0 && threadIdx.x == 0) *counter = 0;   // reset every call

    const int b  = blk / PREP_SLICES;
    const int sl = blk % PREP_SLICES;
    const int t  = threadIdx.x;
    const int wv = t >> 6;   // 0..3

    __shared__ int   hist[4][NUM_LABELS];
    __shared__ float rinv[NUM_LABELS];
    for (int i = t; i < 4 * NUM_LABELS; i += 256) (&hist[0][0])[i] = 0;
    __syncthreads();

    const int* yb = lab + (size_t)b * N_PIX;
    for (int n = t; n < N_PIX; n += 256) atomicAdd(&hist[wv][yb[n]], 1);
    __syncthreads();
    if (t < NUM_LABELS) {
        const int c = hist[0][t] + hist[1][t] + hist[2][t] + hist[3][t];
        rinv[t] = (c > 0) ? 1.0f / (float)c : 0.0f;
    }
    __syncthreads();

    const int n = sl * PREP_PIX + t;     // one pixel per thread
    const float* xb = emb + (size_t)b * C_DIM * N_PIX;
    float v[C_DIM];
    float s = 0.f;
#pragma unroll
    for (int c = 0; c < C_DIM; ++c) { v[c] = xb[c * N_PIX + n]; s += v[c]; }
    const float mean = s * (1.0f / C_DIM);
    float ss = 0.f;
#pragma unroll
    for (int c = 0; c < C_DIM; ++c) { v[c] -= mean; ss += v[c] * v[c]; }
    const float nrm = sqrtf(ss);
    const float w   = rinv[yb[n]];
    const float inv = (nrm > 0.f) ? (w / nrm) : 0.f;

    float* gb = g_out + (size_t)b * C_DIM * N_PIX;
#pragma unroll
    for (int c = 0; c < C_DIM; ++c) gb[c * N_PIX + n] = v[c] * inv;
    w_out[(size_t)b * N_PIX + n] = w;
}

// ---------------- Kernel B: pairwise loss + last-block final reduce ---------
// per UNORDERED pair i<j:  eq ? (w_i w_j - g.g) : max(g.g, 0)
// diagonal i==j:           0.5 * (w_i^2 - g.g)
// (ordered-pair 2x and the 0.5 loss factors are folded together)
__global__ __launch_bounds__(256) void pair_kernel(
    const float* __restrict__ g,     // [B][C][N]
    const float* __restrict__ w,     // [B][N]
    const int*   __restrict__ lab,   // [B][N]
    float* __restrict__ partials,    // [NPAIRBLK]
    int*   __restrict__ counter,
    float* __restrict__ out)
{
    const int k0 = blockIdx.x % PTPAIRS;
    const int b  = blockIdx.x / PTPAIRS;

    // decode upper-triangle tile pair (ti <= tj)
    const float nn = (float)PNT;
    int ti = (int)(((2.f * nn + 1.f) -
                    sqrtf((2.f * nn + 1.f) * (2.f * nn + 1.f) - 8.f * (float)k0)) * 0.5f);
    if (ti < 0) ti = 0;
    if (ti > PNT - 1) ti = PNT - 1;
    auto rowoff = [](int r) { return r * PNT - (r * (r - 1)) / 2; };
    while (ti > 0 && k0 < rowoff(ti)) --ti;
    while (ti < PNT - 1 && k0 >= rowoff(ti + 1)) ++ti;
    const int tj = ti + (k0 - rowoff(ti));
    const bool diag = (ti == tj);

    __shared__ float gI[C_DIM][PTILE];
    __shared__ float gJ[C_DIM][PTILE];
    __shared__ float wI[PTILE], wJ[PTILE];
    __shared__ int   yI[PTILE], yJ[PTILE];

    const int t = threadIdx.x;
    const float* gb = g + (size_t)b * C_DIM * N_PIX;

    for (int idx = t; idx < C_DIM * (PTILE / 4); idx += 256) {
        const int c  = idx >> 5;
        const int qd = idx & 31;
        const float4 vI = *reinterpret_cast<const float4*>(gb + c * N_PIX + ti * PTILE + qd * 4);
        const float4 vJ = *reinterpret_cast<const float4*>(gb + c * N_PIX + tj * PTILE + qd * 4);
        *reinterpret_cast<float4*>(&gI[c][qd * 4]) = vI;
        *reinterpret_cast<float4*>(&gJ[c][qd * 4]) = vJ;
    }
    if (t < PTILE) {
        wI[t] = w[(size_t)b * N_PIX + ti * PTILE + t];
        yI[t] = lab[(size_t)b * N_PIX + ti * PTILE + t];
    } else {
        const int u = t - PTILE;
        wJ[u] = w[(size_t)b * N_PIX + tj * PTILE + u];
        yJ[u] = lab[(size_t)b * N_PIX + tj * PTILE + u];
    }
    __syncthreads();

    const int tI = t >> 4;   // 0..15
    const int tJ = t & 15;   // 0..15

    float acc[8][8];
#pragma unroll
    for (int a = 0; a < 8; ++a)
#pragma unroll
        for (int q = 0; q < 8; ++q) acc[a][q] = 0.f;

#pragma unroll
    for (int c = 0; c < C_DIM; ++c) {
        const float4 a0 = *reinterpret_cast<const float4*>(&gI[c][tI * 8]);
        const float4 a1 = *reinterpret_cast<const float4*>(&gI[c][tI * 8 + 4]);
        const float4 b0 = *reinterpret_cast<const float4*>(&gJ[c][tJ * 8]);
        const float4 b1 = *reinterpret_cast<const float4*>(&gJ[c][tJ * 8 + 4]);
        const float aa[8] = {a0.x, a0.y, a0.z, a0.w, a1.x, a1.y, a1.z, a1.w};
        const float bb[8] = {b0.x, b0.y, b0.z, b0.w, b1.x, b1.y, b1.z, b1.w};
#pragma unroll
        for (int a = 0; a < 8; ++a)
#pragma unroll
            for (int q = 0; q < 8; ++q) acc[a][q] = fmaf(aa[a], bb[q], acc[a][q]);
    }

    float wa[8], wq[8];
    int   ya[8], yq[8];
#pragma unroll
    for (int a = 0; a < 8; ++a) { ya[a] = yI[tI * 8 + a]; wa[a] = wI[tI * 8 + a]; }
#pragma unroll
    for (int q = 0; q < 8; ++q) { yq[q] = yJ[tJ * 8 + q]; wq[q] = wJ[tJ * 8 + q]; }

    float sum = 0.f;
    if (!diag) {
#pragma unroll
        for (int a = 0; a < 8; ++a)
#pragma unroll
            for (int q = 0; q < 8; ++q) {
                const float s = acc[a][q];
                sum += (ya[a] == yq[q]) ? (wa[a] * wq[q] - s) : fmaxf(s, 0.f);
            }
    } else {
#pragma unroll
        for (int a = 0; a < 8; ++a) {
            const int i = tI * 8 + a;
#pragma unroll
            for (int q = 0; q < 8; ++q) {
                const int j = tJ * 8 + q;
                const float s = acc[a][q];
                const float v = (ya[a] == yq[q]) ? (wa[a] * wq[q] - s) : fmaxf(s, 0.f);
                const float f = (i < j) ? 1.f : ((i == j) ? 0.5f : 0.f);
                sum += f * v;
            }
        }
    }

    // block reduction
#pragma unroll
    for (int off = 32; off > 0; off >>= 1) sum += __shfl_down(sum, off);
    __shared__ float wred[4];
    if ((t & 63) == 0) wred[t >> 6] = sum;
    __syncthreads();

    __shared__ int ticket;
    if (t == 0) {
        partials[blockIdx.x] = wred[0] + wred[1] + wred[2] + wred[3];
        __threadfence();                       // release partial
        ticket = atomicAdd(counter, 1);
    }
    __syncthreads();

    if (ticket == NPAIRBLK - 1) {              // last block reduces
        __threadfence();                       // acquire all partials
        const volatile float* vp = (const volatile float*)partials;
        double s = 0.0;
        for (int i = t; i < NPAIRBLK; i += 256) s += (double)vp[i];
        __shared__ double sd[256];
        sd[t] = s;
        __syncthreads();
#pragma unroll
        for (int k = 128; k > 0; k >>= 1) {
            if (t < k) sd[t] += sd[t + k];
            __syncthreads();
        }
        if (t == 0) out[0] = (float)(sd[0] * (1.0 / (double)N_PIX));
    }
}

extern "C" void kernel_launch(void* const* d_in, const int* in_sizes, int n_in,
                              void* d_out, int out_size, void* d_ws, size_t ws_size,
                              hipStream_t stream) {
    const float* emb = (const float*)d_in[0];
    const int*   lab = (const int*)d_in[1];
    float* out = (float*)d_out;

    float* ws = (float*)d_ws;
    float* g_buf    = ws;                                      // B*C*N floats
    float* w_buf    = g_buf + (size_t)BATCH * C_DIM * N_PIX;   // B*N floats
    float* partials = w_buf + (size_t)BATCH * N_PIX;           // NPAIRBLK floats
    int*   counter  = (int*)(partials + NPAIRBLK);

    prep_kernel<<<BATCH * PREP_SLICES, 256, 0, stream>>>(emb, lab, g_buf, w_buf, counter);
    pair_kernel<<<NPAIRBLK, 256, 0, stream>>>(g_buf, w_buf, lab, partials, counter, out);
}

// Round 5
// 22.617 us; speedup vs baseline: 5.3509x; 3.1743x over previous
//
#include <hip/hip_runtime.h>

#define NUM_LABELS 20
#define N_PIX 4096
#define C_DIM 16
#define BATCH 4

#define PTILE 128
#define PNT (N_PIX / PTILE)               // 32
#define PTPAIRS (PNT * (PNT + 1) / 2)     // 528
#define NPAIRBLK (BATCH * PTPAIRS)        // 2112

#define PREP_SLICES 16                    // blocks per batch
#define KPAD 24                           // LDS row stride in shorts (48 B, 16B-aligned)

typedef __attribute__((ext_vector_type(8))) short bf16x8;
typedef __attribute__((ext_vector_type(4))) float f32x4;

__device__ __forceinline__ unsigned int bf16rne(float f) {
    unsigned int x = __float_as_uint(f);
    return (x + 0x7fffu + ((x >> 16) & 1u)) >> 16;
}

// ---------------- Kernel A: histogram + normalize; emit gT (bf16 [B][N][C]) -
// g = (1/cnt[y]) * normalize(center(x));  w = 1/cnt[y]
__global__ __launch_bounds__(256) void prep_kernel(
    const float* __restrict__ emb,         // [B][C][N]
    const int*   __restrict__ lab,         // [B][N]
    unsigned short* __restrict__ gT,       // [B][N][C] bf16
    float* __restrict__ w_out)             // [B][N]
{
    const int blk = blockIdx.x;
    const int b  = blk / PREP_SLICES;
    const int sl = blk % PREP_SLICES;
    const int t  = threadIdx.x;
    const int wv = t >> 6;

    __shared__ int   hist[4][NUM_LABELS];
    __shared__ float rinv[NUM_LABELS];
    __shared__ float xt[C_DIM][256];

    for (int i = t; i < 4 * NUM_LABELS; i += 256) (&hist[0][0])[i] = 0;
    __syncthreads();

    const int* yb = lab + (size_t)b * N_PIX;
    for (int n = t; n < N_PIX; n += 256) atomicAdd(&hist[wv][yb[n]], 1);

    // coalesced stage of this slice's 256 pixels x 16 channels
    const float* xb = emb + (size_t)b * C_DIM * N_PIX + sl * 256;
#pragma unroll
    for (int c = 0; c < C_DIM; ++c) xt[c][t] = xb[(size_t)c * N_PIX + t];
    __syncthreads();

    if (t < NUM_LABELS) {
        const int c = hist[0][t] + hist[1][t] + hist[2][t] + hist[3][t];
        rinv[t] = (c > 0) ? 1.0f / (float)c : 0.0f;
    }
    __syncthreads();

    const int n = sl * 256 + t;
    float v[C_DIM];
    float s = 0.f;
#pragma unroll
    for (int c = 0; c < C_DIM; ++c) { v[c] = xt[c][t]; s += v[c]; }
    const float mean = s * (1.0f / C_DIM);
    float ss = 0.f;
#pragma unroll
    for (int c = 0; c < C_DIM; ++c) { v[c] -= mean; ss += v[c] * v[c]; }
    const float nrm = sqrtf(ss);
    const float wv2 = rinv[yb[n]];
    const float inv = (nrm > 0.f) ? (wv2 / nrm) : 0.f;

    unsigned int u[8];
#pragma unroll
    for (int k = 0; k < 8; ++k) {
        const unsigned int lo = bf16rne(v[2 * k] * inv);
        const unsigned int hi = bf16rne(v[2 * k + 1] * inv);
        u[k] = lo | (hi << 16);
    }
    unsigned int* gp = (unsigned int*)(gT + ((size_t)b * N_PIX + n) * C_DIM);
    *reinterpret_cast<uint4*>(gp)     = make_uint4(u[0], u[1], u[2], u[3]);
    *reinterpret_cast<uint4*>(gp + 4) = make_uint4(u[4], u[5], u[6], u[7]);
    w_out[(size_t)b * N_PIX + n] = wv2;
}

// ---------------- Kernel B: MFMA pairwise loss over upper-triangle tiles ----
// per UNORDERED pair i<j:  eq ? (w_i w_j - s) : max(s, 0),  s = g_i . g_j
// diagonal i==j:           0.5 * (w_i^2 - s)
__global__ __launch_bounds__(256) void pair_kernel(
    const unsigned short* __restrict__ gT, // [B][N][C] bf16
    const float* __restrict__ w,           // [B][N]
    const int*   __restrict__ lab,         // [B][N]
    float* __restrict__ partials)          // [NPAIRBLK]
{
    const int k0 = blockIdx.x % PTPAIRS;
    const int b  = blockIdx.x / PTPAIRS;

    // decode upper-triangle tile pair (ti <= tj)
    const float nn = (float)PNT;
    int ti = (int)(((2.f * nn + 1.f) -
                    sqrtf((2.f * nn + 1.f) * (2.f * nn + 1.f) - 8.f * (float)k0)) * 0.5f);
    if (ti < 0) ti = 0;
    if (ti > PNT - 1) ti = PNT - 1;
    auto rowoff = [](int r) { return r * PNT - (r * (r - 1)) / 2; };
    while (ti > 0 && k0 < rowoff(ti)) --ti;
    while (ti < PNT - 1 && k0 >= rowoff(ti + 1)) ++ti;
    const int tj = ti + (k0 - rowoff(ti));
    const bool diag = (ti == tj);

    __shared__ unsigned short sI[PTILE * KPAD];
    __shared__ unsigned short sJ[PTILE * KPAD];
    __shared__ float swI[PTILE], swJ[PTILE];
    __shared__ int   syI[PTILE], syJ[PTILE];

    const int t = threadIdx.x;
    const unsigned short* gb = gT + (size_t)b * N_PIX * C_DIM;

    {   // stage bf16 tiles: 128 rows x 32 B each, one uint4 per thread per tile
        const int row = t >> 1, half = t & 1;
        const uint4 vI = *(reinterpret_cast<const uint4*>(gb + (size_t)(ti * PTILE + row) * C_DIM) + half);
        const uint4 vJ = *(reinterpret_cast<const uint4*>(gb + (size_t)(tj * PTILE + row) * C_DIM) + half);
        *reinterpret_cast<uint4*>(&sI[row * KPAD + half * 8]) = vI;
        *reinterpret_cast<uint4*>(&sJ[row * KPAD + half * 8]) = vJ;
    }
    if (t < PTILE) {
        swI[t] = w[(size_t)b * N_PIX + ti * PTILE + t];
        syI[t] = lab[(size_t)b * N_PIX + ti * PTILE + t];
    } else {
        const int u = t - PTILE;
        swJ[u] = w[(size_t)b * N_PIX + tj * PTILE + u];
        syJ[u] = lab[(size_t)b * N_PIX + tj * PTILE + u];
    }
    __syncthreads();

    const int wv   = t >> 6;
    const int lane = t & 63;
    const int lo16 = lane & 15;
    const int hi   = lane >> 4;            // 0..3
    const bool doread = (hi < 2);          // lanes holding real K (k<16); rest stay zero

    // A fragments + per-row labels/weights for this wave's two row-tiles
    bf16x8 afrag[2] = {bf16x8{}, bf16x8{}};
    int    yIr[2][4];
    float  wIr[2][4];
#pragma unroll
    for (int rt = 0; rt < 2; ++rt) {
        const int rtile = wv * 2 + rt;
        if (doread)
            afrag[rt] = *reinterpret_cast<const bf16x8*>(&sI[(rtile * 16 + lo16) * KPAD + hi * 8]);
        const int rbase = rtile * 16 + hi * 4;
#pragma unroll
        for (int j = 0; j < 4; ++j) { yIr[rt][j] = syI[rbase + j]; wIr[rt][j] = swI[rbase + j]; }
    }

    float sum = 0.f;
#pragma unroll
    for (int ct = 0; ct < 8; ++ct) {
        bf16x8 bfrag = bf16x8{};
        if (doread)
            bfrag = *reinterpret_cast<const bf16x8*>(&sJ[(ct * 16 + lo16) * KPAD + hi * 8]);
        const int   yq = syJ[ct * 16 + lo16];
        const float wq = swJ[ct * 16 + lo16];
#pragma unroll
        for (int rt = 0; rt < 2; ++rt) {
            const int rtile = wv * 2 + rt;
            if (diag && rtile > ct) continue;          // below diagonal: all zero
            f32x4 acc = {0.f, 0.f, 0.f, 0.f};
            acc = __builtin_amdgcn_mfma_f32_16x16x32_bf16(afrag[rt], bfrag, acc, 0, 0, 0);
            if (diag && rtile == ct) {
#pragma unroll
                for (int j = 0; j < 4; ++j) {
                    const float s  = acc[j];
                    const float v  = (yIr[rt][j] == yq) ? fmaf(wIr[rt][j], wq, -s) : fmaxf(s, 0.f);
                    const int iloc = hi * 4 + j;
                    const float f  = (iloc < lo16) ? 1.f : ((iloc == lo16) ? 0.5f : 0.f);
                    sum += f * v;
                }
            } else {
#pragma unroll
                for (int j = 0; j < 4; ++j) {
                    const float s = acc[j];
                    sum += (yIr[rt][j] == yq) ? fmaf(wIr[rt][j], wq, -s) : fmaxf(s, 0.f);
                }
            }
        }
    }

    // block reduction (wave shuffle + LDS across 4 waves)
#pragma unroll
    for (int off = 32; off > 0; off >>= 1) sum += __shfl_down(sum, off);
    __shared__ float wred[4];
    if (lane == 0) wred[wv] = sum;
    __syncthreads();
    if (t == 0) partials[blockIdx.x] = wred[0] + wred[1] + wred[2] + wred[3];
}

// ---------------- Kernel C: deterministic final reduce ----------------------
__global__ __launch_bounds__(256) void reduce_kernel(
    const float* __restrict__ partials, int n, float* __restrict__ out)
{
    __shared__ double sd[256];
    const int t = threadIdx.x;
    double s = 0.0;
    for (int i = t; i < n; i += 256) s += (double)partials[i];
    sd[t] = s;
    __syncthreads();
#pragma unroll
    for (int k = 128; k > 0; k >>= 1) {
        if (t < k) sd[t] += sd[t + k];
        __syncthreads();
    }
    if (t == 0) out[0] = (float)(sd[0] * (1.0 / (double)N_PIX));
}

extern "C" void kernel_launch(void* const* d_in, const int* in_sizes, int n_in,
                              void* d_out, int out_size, void* d_ws, size_t ws_size,
                              hipStream_t stream) {
    const float* emb = (const float*)d_in[0];
    const int*   lab = (const int*)d_in[1];
    float* out = (float*)d_out;

    unsigned short* gT = (unsigned short*)d_ws;                        // B*N*C bf16
    float* w_buf    = (float*)(gT + (size_t)BATCH * N_PIX * C_DIM);    // B*N floats
    float* partials = w_buf + (size_t)BATCH * N_PIX;                   // NPAIRBLK floats

    prep_kernel<<<BATCH * PREP_SLICES, 256, 0, stream>>>(emb, lab, gT, w_buf);
    pair_kernel<<<NPAIRBLK, 256, 0, stream>>>(gT, w_buf, lab, partials);
    reduce_kernel<<<1, 256, 0, stream>>>(partials, NPAIRBLK, out);
}

// Round 6
// 22.577 us; speedup vs baseline: 5.3605x; 1.0018x over previous
//
#include <hip/hip_runtime.h>

#define NUM_LABELS 20
#define N_PIX 4096
#define C_DIM 16
#define BATCH 4

#define PTILE 128
#define PNT (N_PIX / PTILE)               // 32
#define PTPAIRS (PNT * (PNT + 1) / 2)     // 528
#define NPAIRBLK (BATCH * PTPAIRS)        // 2112

#define PREP_SLICES 16                    // blocks per batch (64 total)
#define NPREP (BATCH * PREP_SLICES)
#define KPAD 24                           // LDS row stride in shorts (48 B)

typedef __attribute__((ext_vector_type(8))) short bf16x8;
typedef __attribute__((ext_vector_type(4))) float f32x4;

__device__ __forceinline__ unsigned int bf16rne(float f) {
    unsigned int x = __float_as_uint(f);
    return (x + 0x7fffu + ((x >> 16) & 1u)) >> 16;
}

// ---------------- Kernel A: histogram + normalize -> gT bf16; sq partials ---
// g = (1/cnt[y]) * normalize(center(x)); sliceSq[blk] = sum |g_f32|^2 over slice;
// presF[b] = #present labels (written by slice 0 of each batch).
__global__ __launch_bounds__(256) void prep_kernel(
    const float* __restrict__ emb,         // [B][C][N]
    const int*   __restrict__ lab,         // [B][N]
    unsigned short* __restrict__ gT,       // [B][N][C] bf16
    float* __restrict__ sliceSq,           // [NPREP]
    float* __restrict__ presF)             // [BATCH]
{
    const int blk = blockIdx.x;
    const int b  = blk / PREP_SLICES;
    const int sl = blk % PREP_SLICES;
    const int t  = threadIdx.x;
    const int wv = t >> 6;
    const int lane = t & 63;

    __shared__ int   hist[4][NUM_LABELS];
    __shared__ float rinv[NUM_LABELS];
    __shared__ float xt[C_DIM][256];
    __shared__ float wsum[4];

    for (int i = t; i < 4 * NUM_LABELS; i += 256) (&hist[0][0])[i] = 0;
    __syncthreads();

    const int* yb = lab + (size_t)b * N_PIX;
    for (int n = t; n < N_PIX; n += 256) atomicAdd(&hist[wv][yb[n]], 1);

    const float* xb = emb + (size_t)b * C_DIM * N_PIX + sl * 256;
#pragma unroll
    for (int c = 0; c < C_DIM; ++c) xt[c][t] = xb[(size_t)c * N_PIX + t];
    __syncthreads();

    if (t < NUM_LABELS) {
        const int c = hist[0][t] + hist[1][t] + hist[2][t] + hist[3][t];
        rinv[t] = (c > 0) ? 1.0f / (float)c : 0.0f;
    }
    __syncthreads();

    if (sl == 0 && t == 0) {
        int p = 0;
#pragma unroll
        for (int l = 0; l < NUM_LABELS; ++l)
            p += (rinv[l] > 0.f) ? 1 : 0;
        presF[b] = (float)p;
    }

    const int n = sl * 256 + t;
    float v[C_DIM];
    float s = 0.f;
#pragma unroll
    for (int c = 0; c < C_DIM; ++c) { v[c] = xt[c][t]; s += v[c]; }
    const float mean = s * (1.0f / C_DIM);
    float ss = 0.f;
#pragma unroll
    for (int c = 0; c < C_DIM; ++c) { v[c] -= mean; ss += v[c] * v[c]; }
    const float nrm = sqrtf(ss);
    const float w   = rinv[yb[n]];
    const float inv = (nrm > 0.f) ? (w / nrm) : 0.f;

    unsigned int u[8];
#pragma unroll
    for (int k = 0; k < 8; ++k) {
        const unsigned int lo = bf16rne(v[2 * k] * inv);
        const unsigned int hi = bf16rne(v[2 * k + 1] * inv);
        u[k] = lo | (hi << 16);
    }
    unsigned int* gp = (unsigned int*)(gT + ((size_t)b * N_PIX + n) * C_DIM);
    *reinterpret_cast<uint4*>(gp)     = make_uint4(u[0], u[1], u[2], u[3]);
    *reinterpret_cast<uint4*>(gp + 4) = make_uint4(u[4], u[5], u[6], u[7]);

    // |g_f32|^2 = inv^2 * ss  (0 for zero-norm pixels)
    float sq = inv * inv * ss;
#pragma unroll
    for (int off = 32; off > 0; off >>= 1) sq += __shfl_down(sq, off);
    if (lane == 0) wsum[wv] = sq;
    __syncthreads();
    if (t == 0) sliceSq[blk] = wsum[0] + wsum[1] + wsum[2] + wsum[3];
}

// ---------------- Kernel B: MFMA pairwise sum over i<j ---------------------
// partial = sum_{i<j in tile-pair} ( y_i==y_j ? -s : max(s,0) ),  s = g_i.g_j
__global__ __launch_bounds__(256) void pair_kernel(
    const unsigned short* __restrict__ gT, // [B][N][C] bf16
    const int*   __restrict__ lab,         // [B][N]
    float* __restrict__ partials)          // [NPAIRBLK]
{
    const int k0 = blockIdx.x % PTPAIRS;
    const int b  = blockIdx.x / PTPAIRS;

    // decode upper-triangle tile pair (ti <= tj)
    const float nn = (float)PNT;
    int ti = (int)(((2.f * nn + 1.f) -
                    sqrtf((2.f * nn + 1.f) * (2.f * nn + 1.f) - 8.f * (float)k0)) * 0.5f);
    if (ti < 0) ti = 0;
    if (ti > PNT - 1) ti = PNT - 1;
    auto rowoff = [](int r) { return r * PNT - (r * (r - 1)) / 2; };
    while (ti > 0 && k0 < rowoff(ti)) --ti;
    while (ti < PNT - 1 && k0 >= rowoff(ti + 1)) ++ti;
    const int tj = ti + (k0 - rowoff(ti));
    const bool diag = (ti == tj);

    __shared__ unsigned short sI[PTILE * KPAD];
    __shared__ unsigned short sJ[PTILE * KPAD];
    __shared__ int syI[PTILE], syJ[PTILE];

    const int t = threadIdx.x;
    const unsigned short* gb = gT + (size_t)b * N_PIX * C_DIM;

    {   // stage bf16 tiles: 128 rows x 32 B, one uint4 per thread per tile
        const int row = t >> 1, half = t & 1;
        const uint4 vI = *(reinterpret_cast<const uint4*>(gb + (size_t)(ti * PTILE + row) * C_DIM) + half);
        const uint4 vJ = *(reinterpret_cast<const uint4*>(gb + (size_t)(tj * PTILE + row) * C_DIM) + half);
        *reinterpret_cast<uint4*>(&sI[row * KPAD + half * 8]) = vI;
        *reinterpret_cast<uint4*>(&sJ[row * KPAD + half * 8]) = vJ;
    }
    if (t < PTILE) {
        syI[t] = lab[(size_t)b * N_PIX + ti * PTILE + t];
    } else {
        const int u = t - PTILE;
        syJ[u] = lab[(size_t)b * N_PIX + tj * PTILE + u];
    }
    __syncthreads();

    const int wv   = t >> 6;
    const int lane = t & 63;
    const int lo16 = lane & 15;
    const int hi   = lane >> 4;            // 0..3
    const bool doread = (hi < 2);          // K=16 real; hi>=2 lanes hold zeros

    bf16x8 afrag[2] = {bf16x8{}, bf16x8{}};
    int    yIr[2][4];
#pragma unroll
    for (int rt = 0; rt < 2; ++rt) {
        const int rtile = wv * 2 + rt;
        if (doread)
            afrag[rt] = *reinterpret_cast<const bf16x8*>(&sI[(rtile * 16 + lo16) * KPAD + hi * 8]);
        const int4 yv = *reinterpret_cast<const int4*>(&syI[rtile * 16 + hi * 4]);
        yIr[rt][0] = yv.x; yIr[rt][1] = yv.y; yIr[rt][2] = yv.z; yIr[rt][3] = yv.w;
    }

    float sum = 0.f;
#pragma unroll
    for (int ct = 0; ct < 8; ++ct) {
        bf16x8 bfrag = bf16x8{};
        if (doread)
            bfrag = *reinterpret_cast<const bf16x8*>(&sJ[(ct * 16 + lo16) * KPAD + hi * 8]);
        const int yq = syJ[ct * 16 + lo16];
#pragma unroll
        for (int rt = 0; rt < 2; ++rt) {
            const int rtile = wv * 2 + rt;
            if (diag && rtile > ct) continue;          // below diagonal: skip
            f32x4 acc = {0.f, 0.f, 0.f, 0.f};
            acc = __builtin_amdgcn_mfma_f32_16x16x32_bf16(afrag[rt], bfrag, acc, 0, 0, 0);
            if (diag && rtile == ct) {
#pragma unroll
                for (int j = 0; j < 4; ++j) {
                    const float s = acc[j];
                    const float r = fmaxf(s, 0.f);
                    const float v = (yIr[rt][j] == yq) ? -s : r;
                    const int iloc = hi * 4 + j;
                    sum += (iloc < lo16) ? v : 0.f;    // strict i<j
                }
            } else {
#pragma unroll
                for (int j = 0; j < 4; ++j) {
                    const float s = acc[j];
                    const float r = fmaxf(s, 0.f);
                    sum += (yIr[rt][j] == yq) ? -s : r;
                }
            }
        }
    }

    // block reduction (wave shuffle + LDS across 4 waves)
#pragma unroll
    for (int off = 32; off > 0; off >>= 1) sum += __shfl_down(sum, off);
    __shared__ float wred[4];
    if (lane == 0) wred[wv] = sum;
    __syncthreads();
    if (t == 0) partials[blockIdx.x] = wred[0] + wred[1] + wred[2] + wred[3];
}

// ---------------- Kernel C: deterministic final reduce + constants ----------
// out = ( sum(partials) + 0.5*sum_b presF[b] - 0.5*sum(sliceSq) ) / N
__global__ __launch_bounds__(256) void reduce_kernel(
    const float* __restrict__ partials,    // [NPAIRBLK]
    const float* __restrict__ sliceSq,     // [NPREP]
    const float* __restrict__ presF,       // [BATCH]
    float* __restrict__ out)
{
    __shared__ double sd[256];
    const int t = threadIdx.x;
    double s = 0.0;
    for (int i = t; i < NPAIRBLK; i += 256) s += (double)partials[i];
    if (t < NPREP) s -= 0.5 * (double)sliceSq[t];
    if (t < BATCH) s += 0.5 * (double)presF[t];
    sd[t] = s;
    __syncthreads();
#pragma unroll
    for (int k = 128; k > 0; k >>= 1) {
        if (t < k) sd[t] += sd[t + k];
        __syncthreads();
    }
    if (t == 0) out[0] = (float)(sd[0] * (1.0 / (double)N_PIX));
}

extern "C" void kernel_launch(void* const* d_in, const int* in_sizes, int n_in,
                              void* d_out, int out_size, void* d_ws, size_t ws_size,
                              hipStream_t stream) {
    const float* emb = (const float*)d_in[0];
    const int*   lab = (const int*)d_in[1];
    float* out = (float*)d_out;

    unsigned short* gT = (unsigned short*)d_ws;                        // B*N*C bf16
    float* sliceSq  = (float*)(gT + (size_t)BATCH * N_PIX * C_DIM);    // NPREP
    float* presF    = sliceSq + NPREP;                                 // BATCH
    float* partials = presF + BATCH;                                   // NPAIRBLK

    prep_kernel<<<NPREP, 256, 0, stream>>>(emb, lab, gT, sliceSq, presF);
    pair_kernel<<<NPAIRBLK, 256, 0, stream>>>(gT, lab, partials);
    reduce_kernel<<<1, 256, 0, stream>>>(partials, sliceSq, presF, out);
}